// Round 5
// baseline (2457.999 us; speedup 1.0000x reference)
//
#include <hip/hip_runtime.h>
#include <stdint.h>

typedef unsigned short ushortT;
typedef float f32x4 __attribute__((ext_vector_type(4)));
typedef short short8 __attribute__((ext_vector_type(8)));

#define HID 3584
#define NH 16
#define NKV 8
#define DH 256
#define SEQ 2048
#define NB 2
#define NTOK 4096
#define INTERDIM 14336
#define ICH 7168  // FFN chunk of INTER
#define WINDOW 1024

__device__ __forceinline__ ushortT f2bf(float x) {
  union { float f; uint32_t u; } v; v.f = x;
  uint32_t r = v.u + 0x7fffu + ((v.u >> 16) & 1u);
  return (ushortT)(r >> 16);
}
__device__ __forceinline__ float bf2f(uint32_t b) {
  union { uint32_t u; float f; } v; v.u = b << 16;
  return v.f;
}
__device__ __forceinline__ void gll16(const void* g, void* l) {
  __builtin_amdgcn_global_load_lds((const __attribute__((address_space(1))) void*)g,
                                   (__attribute__((address_space(3))) void*)l, 16, 0, 0);
}
__device__ __forceinline__ void sbar() {
  asm volatile("" ::: "memory");
  __builtin_amdgcn_s_barrier();
  asm volatile("" ::: "memory");
}

// ---------------- transpose + fp32->bf16 convert: out[c][r] = in[r][c] ----------------
__global__ __launch_bounds__(256) void transpose_cvt(const float* __restrict__ in,
                                                     ushortT* __restrict__ out,
                                                     int in_rs, int out_rs) {
  __shared__ float tile[64][65];
  const int r0 = blockIdx.y * 64, c0 = blockIdx.x * 64;
  const int t = threadIdx.x, tc = (t & 15) * 4, tr = t >> 4;
#pragma unroll
  for (int p = 0; p < 4; ++p) {
    int r = tr + p * 16;
    float4 v = *(const float4*)&in[(size_t)(r0 + r) * in_rs + c0 + tc];
    tile[r][tc] = v.x; tile[r][tc + 1] = v.y; tile[r][tc + 2] = v.z; tile[r][tc + 3] = v.w;
  }
  __syncthreads();
#pragma unroll
  for (int p = 0; p < 4; ++p) {
    int r = tr + p * 16;
    ushort4 u;
    u.x = f2bf(tile[tc + 0][r]); u.y = f2bf(tile[tc + 1][r]);
    u.z = f2bf(tile[tc + 2][r]); u.w = f2bf(tile[tc + 3][r]);
    *(ushort4*)&out[(size_t)(c0 + r) * out_rs + r0 + tc] = u;
  }
}

// V transpose: vsrc fp32 [(b*S+s)*2048 + n*256 + d] -> vT bf16 [((b*8+n)*256 + d)*2048 + s]
__global__ __launch_bounds__(256) void vtrans(const float* __restrict__ vsrc,
                                              ushortT* __restrict__ vT) {
  __shared__ float tile[64][65];
  const int z = blockIdx.z, b = z >> 3, n = z & 7;
  const float* in = vsrc + (size_t)b * SEQ * (NKV * DH) + n * DH;
  ushortT* out = vT + (size_t)z * DH * SEQ;
  const int s0 = blockIdx.y * 64, d0 = blockIdx.x * 64;
  const int t = threadIdx.x, tc = (t & 15) * 4, tr = t >> 4;
#pragma unroll
  for (int p = 0; p < 4; ++p) {
    int r = tr + p * 16;
    float4 v = *(const float4*)&in[(size_t)(s0 + r) * (NKV * DH) + d0 + tc];
    tile[r][tc] = v.x; tile[r][tc + 1] = v.y; tile[r][tc + 2] = v.z; tile[r][tc + 3] = v.w;
  }
  __syncthreads();
#pragma unroll
  for (int p = 0; p < 4; ++p) {
    int r = tr + p * 16;
    ushort4 u;
    u.x = f2bf(tile[tc + 0][r]); u.y = f2bf(tile[tc + 1][r]);
    u.z = f2bf(tile[tc + 2][r]); u.w = f2bf(tile[tc + 3][r]);
    *(ushort4*)&out[(size_t)(d0 + r) * SEQ + s0 + tc] = u;
  }
}

// ---------------- RMSNorm family (448 threads, 8 cols/thread) ----------------
__device__ __forceinline__ float block_sum448(float v, float* sb) {
#pragma unroll
  for (int o = 32; o; o >>= 1) v += __shfl_xor(v, o, 64);
  __syncthreads();
  if ((threadIdx.x & 63) == 0) sb[threadIdx.x >> 6] = v;
  __syncthreads();
  float s = 0.f;
#pragma unroll
  for (int i = 0; i < 7; ++i) s += sb[i];
  return s;
}

__global__ __launch_bounds__(448) void rms_in(const float* __restrict__ in,
                                              const float* __restrict__ w,
                                              ushortT* __restrict__ out) {
  __shared__ float sb[8];
  const size_t row = blockIdx.x;
  const int c = threadIdx.x * 8;
  const float* p = in + row * HID + c;
  float4 a = *(const float4*)p, bq = *(const float4*)(p + 4);
  float v[8] = {a.x, a.y, a.z, a.w, bq.x, bq.y, bq.z, bq.w};
  float ssq = 0.f;
#pragma unroll
  for (int j = 0; j < 8; ++j) ssq += v[j] * v[j];
  float s = block_sum448(ssq, sb);
  float rs = rsqrtf(s * (1.0f / HID) + 1e-6f);
  uint32_t o[4];
#pragma unroll
  for (int j = 0; j < 4; ++j) {
    float r0 = v[2 * j] * rs * (1.f + w[c + 2 * j]);
    float r1 = v[2 * j + 1] * rs * (1.f + w[c + 2 * j + 1]);
    o[j] = (uint32_t)f2bf(r0) | ((uint32_t)f2bf(r1) << 16);
  }
  *(uint4*)(out + row * HID + c) = make_uint4(o[0], o[1], o[2], o[3]);
}

// NOTE: ao and resid alias (in-place in out_res) -> NO __restrict__ on them.
__global__ __launch_bounds__(448) void rms_add(const float* ao,
                                               const float* __restrict__ h,
                                               const float* __restrict__ w1,
                                               const float* __restrict__ w2,
                                               float* resid,
                                               ushortT* __restrict__ x2) {
  __shared__ float sb[8];
  const size_t row = blockIdx.x;
  const int c = threadIdx.x * 8;
  const float* p = ao + row * HID + c;
  float4 a = *(const float4*)p, bq = *(const float4*)(p + 4);
  float v[8] = {a.x, a.y, a.z, a.w, bq.x, bq.y, bq.z, bq.w};
  float ssq = 0.f;
#pragma unroll
  for (int j = 0; j < 8; ++j) ssq += v[j] * v[j];
  float s1 = block_sum448(ssq, sb);
  float rs1 = rsqrtf(s1 * (1.0f / HID) + 1e-6f);
  const float* hp = h + row * HID + c;
  float4 h0 = *(const float4*)hp, h1 = *(const float4*)(hp + 4);
  float hv[8] = {h0.x, h0.y, h0.z, h0.w, h1.x, h1.y, h1.z, h1.w};
  float r[8];
  float ssq2 = 0.f;
#pragma unroll
  for (int j = 0; j < 8; ++j) {
    r[j] = hv[j] + v[j] * rs1 * (1.f + w1[c + j]);
    ssq2 += r[j] * r[j];
  }
  float* rp = resid + row * HID + c;
  *(float4*)rp = make_float4(r[0], r[1], r[2], r[3]);
  *(float4*)(rp + 4) = make_float4(r[4], r[5], r[6], r[7]);
  float s2 = block_sum448(ssq2, sb);
  float rs2 = rsqrtf(s2 * (1.0f / HID) + 1e-6f);
  uint32_t o[4];
#pragma unroll
  for (int j = 0; j < 4; ++j) {
    float q0 = r[2 * j] * rs2 * (1.f + w2[c + 2 * j]);
    float q1 = r[2 * j + 1] * rs2 * (1.f + w2[c + 2 * j + 1]);
    o[j] = (uint32_t)f2bf(q0) | ((uint32_t)f2bf(q1) << 16);
  }
  *(uint4*)(x2 + row * HID + c) = make_uint4(o[0], o[1], o[2], o[3]);
}

// NOTE: in and out alias (in-place on out_x) -> NO __restrict__.
__global__ __launch_bounds__(448) void rms_out(const float* in,
                                               const float* __restrict__ w,
                                               float* out) {
  __shared__ float sb[8];
  const size_t row = blockIdx.x;
  const int c = threadIdx.x * 8;
  const float* p = in + row * HID + c;
  float4 a = *(const float4*)p, bq = *(const float4*)(p + 4);
  float v[8] = {a.x, a.y, a.z, a.w, bq.x, bq.y, bq.z, bq.w};
  float ssq = 0.f;
#pragma unroll
  for (int j = 0; j < 8; ++j) ssq += v[j] * v[j];
  float s = block_sum448(ssq, sb);
  float rs = rsqrtf(s * (1.0f / HID) + 1e-6f);
  float* op = out + row * HID + c;
  float r[8];
#pragma unroll
  for (int j = 0; j < 8; ++j) r[j] = v[j] * rs * (1.f + w[c + j]);
  *(float4*)op = make_float4(r[0], r[1], r[2], r[3]);
  *(float4*)(op + 4) = make_float4(r[4], r[5], r[6], r[7]);
}

// ---------------- RoPE (bf16 in) ----------------
__global__ __launch_bounds__(128) void rope_q_k(const ushortT* __restrict__ qraw,
                                                const int* __restrict__ pos,
                                                ushortT* __restrict__ qr) {
  const int s = blockIdx.x, h = blockIdx.y, b = blockIdx.z, i = threadIdx.x;
  float p = (float)pos[b * SEQ + s];
  float ang = p * exp2f(-(float)i * (13.287712379549449f / 128.f));
  float sn, cs;
  sincosf(ang, &sn, &cs);
  size_t ib = ((size_t)b * SEQ + s) * (NH * DH) + (size_t)h * DH + i;
  float x1 = bf2f(qraw[ib]), x2 = bf2f(qraw[ib + 128]);
  size_t ob = (((size_t)b * NH + h) * SEQ + s) * DH + i;
  qr[ob] = f2bf(x1 * cs - x2 * sn);
  qr[ob + 128] = f2bf(x2 * cs + x1 * sn);
}

__global__ __launch_bounds__(128) void rope_k_k(const ushortT* __restrict__ kraw,
                                                const int* __restrict__ pos,
                                                ushortT* __restrict__ kr,
                                                float* __restrict__ kv0) {
  const int s = blockIdx.x, n = blockIdx.y, b = blockIdx.z, i = threadIdx.x;
  float p = (float)pos[b * SEQ + s];
  float ang = p * exp2f(-(float)i * (13.287712379549449f / 128.f));
  float sn, cs;
  sincosf(ang, &sn, &cs);
  size_t ib = ((size_t)b * SEQ + s) * (NKV * DH) + (size_t)n * DH + i;
  float x1 = bf2f(kraw[ib]), x2 = bf2f(kraw[ib + 128]);
  float o1 = x1 * cs - x2 * sn, o2 = x2 * cs + x1 * sn;
  size_t ob = (((size_t)b * NKV + n) * SEQ + s) * DH + i;
  kr[ob] = f2bf(o1);
  kr[ob + 128] = f2bf(o2);
  size_t kb = (((size_t)b * SEQ + s) * NKV + n) * DH + i;
  kv0[kb] = o1;
  kv0[kb + 128] = o2;
}

// ---------------- 256x128 GEMM, BK=64, 8 waves, 3-buffer counted-vmcnt ----------------
// C[M][N](op) = A[M][K](bf16,lda) * Bt[N][K](bf16,ldb)
// LDS: 3 bufs x (A 256x64 = 32KB + B 128x64 = 16KB) = 144 KiB.
// Swizzle: 16B chunk c of row r stored at chunk c^(r&7); inverse-swz source, swz read.
// Per K-tile t: 2 phases (ks=0/1). Phase = {10 ds_read_b128; 3 gll16 of tile t+2;
//   s_barrier; lgkmcnt(0); setprio(1); 16 indep MFMA; setprio(0); s_barrier}.
// Gate: vmcnt(6) once per tile at end of phase B: allows tile t+2's 6 loads in
//   flight, guarantees tile t+1 (older) fully landed (in-order vmcnt accounting).
// Race-free: stage of tile t+2 -> buf[(t+2)%3], last read by tile t-1's phases,
//   which completed before the gate barrier preceding the stage issue.
template <int OUTMODE>  // 0 = fp32 store, 1 = bf16 store, 2 = fp32 accumulate
__global__ __launch_bounds__(512) void gemm256(const ushortT* __restrict__ A, int lda,
                                               const ushortT* __restrict__ Bt, int ldb,
                                               void* __restrict__ C, int N, int K) {
  __shared__ ushortT lds[73728];  // 147456 B = 3 x 49152
  char* lb = (char*)lds;
  const int tid = threadIdx.x;
  // bijective XCD swizzle (all grids here are multiples of 8)
  const int nwg = gridDim.x * gridDim.y;
  const int lin = blockIdx.y * gridDim.x + blockIdx.x;
  const int cpx = nwg >> 3;
  const int lin2 = (lin & 7) * cpx + (lin >> 3);
  const int bx = lin2 % gridDim.x, by = lin2 / gridDim.x;
  const int m0 = by * 256, n0 = bx * 128;
  const int l = tid & 63, lr = l & 15, lg = l >> 4;
  const int wid = tid >> 6, wm = wid >> 2, wn = wid & 3;
  const int sr = tid >> 3, sc = tid & 7;  // staging: row-in-64, chunk 0..7

  f32x4 acc[8][2];
#pragma unroll
  for (int i = 0; i < 8; ++i)
#pragma unroll
    for (int j = 0; j < 2; ++j) acc[i][j] = (f32x4){0.f, 0.f, 0.f, 0.f};

  const int nt = K >> 6;
  const ushortT* Ag = A + (size_t)m0 * lda;
  const ushortT* Bg = Bt + (size_t)n0 * ldb;

  // stage A rounds {h*2, h*2+1} (128 rows) of K-tile tt
  auto stageA2 = [&](int tt, int h) {
    char* dst = lb + (tt % 3) * 49152;
    const ushortT* g = Ag + (size_t)tt * 64;
#pragma unroll
    for (int rr = 0; rr < 2; ++rr) {
      int rnd = h * 2 + rr;
      int row = rnd * 64 + sr;
      gll16((const char*)(g + (size_t)row * lda) + ((sc ^ (row & 7)) << 4),
            dst + rnd * 8192 + tid * 16);
    }
  };
  // stage B round h (64 rows) of K-tile tt
  auto stageB1 = [&](int tt, int h) {
    char* dst = lb + (tt % 3) * 49152 + 32768;
    const ushortT* g = Bg + (size_t)tt * 64;
    int row = h * 64 + sr;
    gll16((const char*)(g + (size_t)row * ldb) + ((sc ^ (row & 7)) << 4),
          dst + h * 8192 + tid * 16);
  };

  // prologue: tiles 0 and 1 (6 loads each)
  stageA2(0, 0); stageB1(0, 0); stageA2(0, 1); stageB1(0, 1);
  stageA2(1, 0); stageB1(1, 0); stageA2(1, 1); stageB1(1, 1);
  asm volatile("s_waitcnt vmcnt(6)" ::: "memory");  // tile 0 landed
  sbar();

  for (int t = 0; t < nt; ++t) {
    const char* Ab = lb + (t % 3) * 49152;
    const char* Bb = Ab + 32768;
    short8 af[8], bf[2];
#pragma unroll
    for (int ks = 0; ks < 2; ++ks) {
      // ds-reads for this phase's MFMA
#pragma unroll
      for (int i = 0; i < 8; ++i) {
        int r = wm * 128 + i * 16 + lr;
        af[i] = *(const short8*)(Ab + r * 128 + (((ks * 4 + lg) ^ (r & 7)) << 4));
      }
#pragma unroll
      for (int j = 0; j < 2; ++j) {
        int r = wn * 32 + j * 16 + lr;
        bf[j] = *(const short8*)(Bb + r * 128 + (((ks * 4 + lg) ^ (r & 7)) << 4));
      }
      // stage half of tile t+2 (3 gll16)
      if (t + 2 < nt) { stageA2(t + 2, ks); stageB1(t + 2, ks); }
      sbar();
      asm volatile("s_waitcnt lgkmcnt(0)" ::: "memory");
      __builtin_amdgcn_sched_barrier(0);
      __builtin_amdgcn_s_setprio(1);
#pragma unroll
      for (int i = 0; i < 8; ++i)
#pragma unroll
        for (int j = 0; j < 2; ++j)
          acc[i][j] = __builtin_amdgcn_mfma_f32_16x16x32_bf16(af[i], bf[j], acc[i][j], 0, 0, 0);
      __builtin_amdgcn_s_setprio(0);
      if (ks == 1 && t + 1 < nt) {
        // gate tile t+1 before next iteration's reads (counted; 0 only at tail)
        if (t + 2 < nt) asm volatile("s_waitcnt vmcnt(6)" ::: "memory");
        else            asm volatile("s_waitcnt vmcnt(0)" ::: "memory");
      }
      sbar();
    }
  }
#pragma unroll
  for (int mi = 0; mi < 8; ++mi)
#pragma unroll
    for (int nj = 0; nj < 2; ++nj)
#pragma unroll
      for (int r = 0; r < 4; ++r) {
        size_t row = (size_t)(m0 + wm * 128 + mi * 16 + lg * 4 + r);
        size_t col = (size_t)(n0 + wn * 32 + nj * 16 + lr);
        if (OUTMODE == 0)
          ((float*)C)[row * N + col] = acc[mi][nj][r];
        else if (OUTMODE == 1)
          ((ushortT*)C)[row * N + col] = f2bf(acc[mi][nj][r]);
        else
          ((float*)C)[row * N + col] += acc[mi][nj][r];
      }
}

// ---------------- swiglu: o = up * gelu_tanh(gate), all bf16 ----------------
__global__ __launch_bounds__(256) void swiglu_k(const ushortT* __restrict__ g,
                                                const ushortT* __restrict__ u,
                                                ushortT* __restrict__ o, int n16) {
  int i = blockIdx.x * 256 + threadIdx.x;
  if (i >= n16) return;
  uint4 gv = ((const uint4*)g)[i];
  uint4 uv = ((const uint4*)u)[i];
  uint32_t ga[4] = {gv.x, gv.y, gv.z, gv.w};
  uint32_t ua[4] = {uv.x, uv.y, uv.z, uv.w};
  uint32_t rr[4];
#pragma unroll
  for (int j = 0; j < 4; ++j) {
    float g0 = bf2f(ga[j] & 0xffffu), g1 = bf2f(ga[j] >> 16);
    float u0 = bf2f(ua[j] & 0xffffu), u1 = bf2f(ua[j] >> 16);
    float e0 = 0.5f * g0 * (1.f + tanhf(0.7978845608f * (g0 + 0.044715f * g0 * g0 * g0)));
    float e1 = 0.5f * g1 * (1.f + tanhf(0.7978845608f * (g1 + 0.044715f * g1 * g1 * g1)));
    rr[j] = (uint32_t)f2bf(u0 * e0) | ((uint32_t)f2bf(u1 * e1) << 16);
  }
  ((uint4*)o)[i] = make_uint4(rr[0], rr[1], rr[2], rr[3]);
}

// ---------------- flash attention (sliding window 1024, causal, softcap 50) ----------------
__global__ __launch_bounds__(256) void attn_fwd(const ushortT* __restrict__ Q,   // [B][H][S][DH]
                                                const ushortT* __restrict__ Kk,  // [B][KV][S][DH]
                                                const ushortT* __restrict__ Vt,  // [B][KV][DH][S]
                                                ushortT* __restrict__ Out) {     // [B*S][H*DH]
  __shared__ ushortT Kl[32 * 256];
  __shared__ ushortT Vl[256 * 32];
  __shared__ ushortT Pl[4][16 * 32];
  const int tid = threadIdx.x;
  const int w = tid >> 6, l = tid & 63, lr = l & 15, lg = l >> 4;
  const int h = blockIdx.y, b = blockIdx.z;
  const int n = h >> 1;
  const int qs = blockIdx.x * 64;
  const int sw = qs + w * 16;

  const ushortT* qp = Q + (((size_t)b * NH + h) * SEQ + (sw + lr)) * DH;
  short8 qf[8];
#pragma unroll
  for (int kk = 0; kk < 8; ++kk) qf[kk] = *(const short8*)(qp + kk * 32 + lg * 8);

  f32x4 acc[16];
#pragma unroll
  for (int i = 0; i < 16; ++i) acc[i] = (f32x4){0.f, 0.f, 0.f, 0.f};
  float m_s = -1e30f, l_s = 0.f;

  const ushortT* Kbase = Kk + ((size_t)b * NKV + n) * SEQ * DH;
  const ushortT* Vbase = Vt + ((size_t)b * NKV + n) * DH * SEQ;

  int tlo = qs - (WINDOW - 1);
  if (tlo < 0) tlo = 0;
  const int t0b = tlo & ~31;
  const int nt = (qs + 64 - t0b) >> 5;
  const int scol = sw + lr;

  for (int it = 0; it < nt; ++it) {
    const int t0 = t0b + it * 32;
    __syncthreads();
    {
      const int rowk = tid >> 5;
      const int cbk = (tid & 31) * 16;
#pragma unroll
      for (int c = 0; c < 4; ++c) {
        int row = c * 8 + rowk;
        int cbs = cbk ^ ((row & 7) << 4);
        gll16((const char*)(Kbase + (size_t)(t0 + row) * DH) + cbs, (char*)Kl + c * 4096 + tid * 16);
      }
      const int rowv = tid >> 2;
      const int cbv = (tid & 3) * 16;
#pragma unroll
      for (int c = 0; c < 4; ++c) {
        int row = c * 64 + rowv;
        int cbs = cbv ^ ((row & 3) << 4);
        gll16((const char*)(Vbase + (size_t)row * SEQ + t0) + cbs, (char*)Vl + c * 4096 + tid * 16);
      }
    }
    __syncthreads();
    f32x4 st[2];
#pragma unroll
    for (int tt = 0; tt < 2; ++tt) {
      f32x4 a = (f32x4){0.f, 0.f, 0.f, 0.f};
      const int krow = tt * 16 + lr;
      const char* kb = (const char*)Kl + krow * 512;
      const int swz = (krow & 7) << 4;
#pragma unroll
      for (int kk = 0; kk < 8; ++kk) {
        short8 kf = *(const short8*)(kb + ((kk * 64 + lg * 16) ^ swz));
        a = __builtin_amdgcn_mfma_f32_16x16x32_bf16(kf, qf[kk], a, 0, 0, 0);
      }
      st[tt] = a;
    }
    float pvv[8];
    float tmax = -1e30f;
#pragma unroll
    for (int tt = 0; tt < 2; ++tt)
#pragma unroll
      for (int r = 0; r < 4; ++r) {
        int t = t0 + tt * 16 + lg * 4 + r;
        float x = st[tt][r] * 0.0625f;
        x = 50.f * tanhf(x * 0.02f);
        bool ok = (t <= scol) && (scol - t < WINDOW);
        x = ok ? x : -1e30f;
        pvv[tt * 4 + r] = x;
        tmax = fmaxf(tmax, x);
      }
    tmax = fmaxf(tmax, __shfl_xor(tmax, 16, 64));
    tmax = fmaxf(tmax, __shfl_xor(tmax, 32, 64));
    float mnew = fmaxf(m_s, tmax);
    float fsc = __expf(m_s - mnew);
    m_s = mnew;
    float tsum = 0.f;
#pragma unroll
    for (int i = 0; i < 8; ++i) {
      pvv[i] = __expf(pvv[i] - mnew);
      tsum += pvv[i];
    }
    tsum += __shfl_xor(tsum, 16, 64);
    tsum += __shfl_xor(tsum, 32, 64);
    l_s = l_s * fsc + tsum;
    {
      char* pb = (char*)&Pl[w][0] + lr * 64;
      const int pswz = (lr & 3) << 4;
#pragma unroll
      for (int tt = 0; tt < 2; ++tt) {
        uint32_t p01 = (uint32_t)f2bf(pvv[tt * 4 + 0]) | ((uint32_t)f2bf(pvv[tt * 4 + 1]) << 16);
        uint32_t p23 = (uint32_t)f2bf(pvv[tt * 4 + 2]) | ((uint32_t)f2bf(pvv[tt * 4 + 3]) << 16);
        *(uint32_t*)(pb + ((tt * 32 + lg * 8 + 0) ^ pswz)) = p01;
        *(uint32_t*)(pb + ((tt * 32 + lg * 8 + 4) ^ pswz)) = p23;
      }
    }
    float fr[4];
#pragma unroll
    for (int r = 0; r < 4; ++r) fr[r] = __shfl(fsc, lg * 4 + r, 64);
#pragma unroll
    for (int nd = 0; nd < 16; ++nd) {
      acc[nd][0] *= fr[0]; acc[nd][1] *= fr[1];
      acc[nd][2] *= fr[2]; acc[nd][3] *= fr[3];
    }
    const char* pfb = (const char*)&Pl[w][0] + lr * 64;
    short8 pf = *(const short8*)(pfb + ((lg * 16) ^ ((lr & 3) << 4)));
#pragma unroll
    for (int nd = 0; nd < 16; ++nd) {
      const int vrow = nd * 16 + lr;
      short8 vf = *(const short8*)((const char*)Vl + vrow * 64 + ((lg * 16) ^ ((vrow & 3) << 4)));
      acc[nd] = __builtin_amdgcn_mfma_f32_16x16x32_bf16(pf, vf, acc[nd], 0, 0, 0);
    }
  }
  float linv[4];
#pragma unroll
  for (int r = 0; r < 4; ++r) linv[r] = 1.f / __shfl(l_s, lg * 4 + r, 64);
#pragma unroll
  for (int nd = 0; nd < 16; ++nd)
#pragma unroll
    for (int r = 0; r < 4; ++r) {
      size_t row = (size_t)b * SEQ + sw + lg * 4 + r;
      Out[row * (NH * DH) + (size_t)h * DH + nd * 16 + lr] = f2bf(acc[nd][r] * linv[r]);
    }
}

// ---------------- host ----------------
extern "C" void kernel_launch(void* const* d_in, const int* in_sizes, int n_in,
                              void* d_out, int out_size, void* d_ws, size_t ws_size,
                              hipStream_t stream) {
  const float* hs = (const float*)d_in[0];
  const int* pos = (const int*)d_in[1];
  const float* w_in = (const float*)d_in[2];
  const float* w_pa = (const float*)d_in[3];
  const float* w_pf = (const float*)d_in[4];
  const float* w_po = (const float*)d_in[5];
  const float* qw = (const float*)d_in[6];
  const float* kw = (const float*)d_in[7];
  const float* vw = (const float*)d_in[8];
  const float* ow = (const float*)d_in[9];
  const float* gw = (const float*)d_in[10];
  const float* uw = (const float*)d_in[11];
  const float* dw = (const float*)d_in[12];

  float* out_x = (float*)d_out;
  float* out_res = out_x + (size_t)NTOK * HID;
  float* out_kv0 = out_res + (size_t)NTOK * HID;
  float* out_kv1 = out_kv0 + (size_t)NTOK * NKV * DH;

  char* ws = (char*)d_ws;
  // W region
  char* W = ws;
  ushortT* qwT = (ushortT*)(W);
  ushortT* kwT = (ushortT*)(W + 29360128);
  ushortT* vwT = (ushortT*)(W + 29360128 + 14680064);
  ushortT* owT = (ushortT*)(W + 29360128 + 2 * 14680064);
  ushortT* wS0 = (ushortT*)(W);              // 51,380,224 B
  ushortT* wS1 = (ushortT*)(W + 51380224);   // 51,380,224 B
  // R region
  char* R = ws + 102760448;
  ushortT* x1 = (ushortT*)(R);                           // 29,360,128
  ushortT* qraw_b = (ushortT*)(R + 29360128);            // 33,554,432 (A)
  ushortT* kraw_b = (ushortT*)(R + 62914560);            // 16,777,216 (B)
  ushortT* qrope = (ushortT*)(R + 79691776);             // 33,554,432 (C)
  ushortT* krope = (ushortT*)(R + 113246208);            // 16,777,216 (D)
  ushortT* vT = (ushortT*)(R + 130023424);               // 16,777,216 (E)
  ushortT* attnb = qraw_b;
  ushortT* x2 = x1;
  ushortT* gateC = (ushortT*)(R + 29360128);             // 58,720,256
  ushortT* upC = (ushortT*)(R + 29360128 + 58720256);    // 58,720,256
  ushortT* interC = gateC;
  float* attn_out = out_res;

  // --- phase 1: attention weights -> bf16 transposed ---
  transpose_cvt<<<dim3(4096 / 64, HID / 64), 256, 0, stream>>>(qw, qwT, 4096, HID);
  transpose_cvt<<<dim3(2048 / 64, HID / 64), 256, 0, stream>>>(kw, kwT, 2048, HID);
  transpose_cvt<<<dim3(2048 / 64, HID / 64), 256, 0, stream>>>(vw, vwT, 2048, HID);
  transpose_cvt<<<dim3(HID / 64, 4096 / 64), 256, 0, stream>>>(ow, owT, HID, 4096);

  // --- phase 2: input rmsnorm ---
  rms_in<<<NTOK, 448, 0, stream>>>(hs, w_in, x1);

  // --- phase 3: qkv projections (v -> out_kv1 fp32 directly) ---
  gemm256<1><<<dim3(32, 16), 512, 0, stream>>>(x1, HID, qwT, HID, qraw_b, 4096, HID);
  gemm256<1><<<dim3(16, 16), 512, 0, stream>>>(x1, HID, kwT, HID, kraw_b, 2048, HID);
  gemm256<0><<<dim3(16, 16), 512, 0, stream>>>(x1, HID, vwT, HID, out_kv1, 2048, HID);

  // --- phase 4: rope (+kv_fused k out) + V transpose ---
  rope_q_k<<<dim3(SEQ, NH, NB), 128, 0, stream>>>(qraw_b, pos, qrope);
  rope_k_k<<<dim3(SEQ, NKV, NB), 128, 0, stream>>>(kraw_b, pos, krope, out_kv0);
  vtrans<<<dim3(DH / 64, SEQ / 64, NB * NKV), 256, 0, stream>>>(out_kv1, vT);

  // --- phase 5: attention ---
  attn_fwd<<<dim3(SEQ / 64, NH, NB), 256, 0, stream>>>(qrope, krope, vT, attnb);

  // --- phase 6: output projection (into out_res region) ---
  gemm256<0><<<dim3(HID / 128, 16), 512, 0, stream>>>(attnb, 4096, owT, 4096, attn_out, HID, 4096);

  // --- phase 7: post-attn norm + residual (in-place) + pre-ff norm ---
  rms_add<<<NTOK, 448, 0, stream>>>(attn_out, hs, w_pa, w_pf, out_res, x2);

  // --- phases 8-10: FFN in 2 chunks of 7168, down accumulates into out_x ---
  for (int c = 0; c < 2; ++c) {
    transpose_cvt<<<dim3(ICH / 64, HID / 64), 256, 0, stream>>>(gw + (size_t)c * ICH, wS0,
                                                                INTERDIM, HID);
    gemm256<1><<<dim3(ICH / 128, 16), 512, 0, stream>>>(x2, HID, wS0, HID, gateC, ICH, HID);
    transpose_cvt<<<dim3(ICH / 64, HID / 64), 256, 0, stream>>>(uw + (size_t)c * ICH, wS1,
                                                                INTERDIM, HID);
    gemm256<1><<<dim3(ICH / 128, 16), 512, 0, stream>>>(x2, HID, wS1, HID, upC, ICH, HID);
    int n16 = (int)((size_t)NTOK * ICH / 8);
    swiglu_k<<<(n16 + 255) / 256, 256, 0, stream>>>(gateC, upC, interC, n16);
    transpose_cvt<<<dim3(HID / 64, ICH / 64), 256, 0, stream>>>(dw + (size_t)c * ICH * HID, wS0,
                                                                HID, ICH);
    if (c == 0)
      gemm256<0><<<dim3(HID / 128, 16), 512, 0, stream>>>(interC, ICH, wS0, ICH, out_x, HID, ICH);
    else
      gemm256<2><<<dim3(HID / 128, 16), 512, 0, stream>>>(interC, ICH, wS0, ICH, out_x, HID, ICH);
  }

  // --- phase 11: final norm (in-place on out_x) ---
  rms_out<<<NTOK, 448, 0, stream>>>(out_x, w_po, out_x);
}

// Round 6
// 2333.911 us; speedup vs baseline: 1.0532x; 1.0532x over previous
//
#include <hip/hip_runtime.h>
#include <stdint.h>

typedef unsigned short ushortT;
typedef float f32x4 __attribute__((ext_vector_type(4)));
typedef short short8 __attribute__((ext_vector_type(8)));

#define HID 3584
#define NH 16
#define NKV 8
#define DH 256
#define SEQ 2048
#define NB 2
#define NTOK 4096
#define INTERDIM 14336
#define ICH 7168  // FFN chunk of INTER
#define WINDOW 1024

__device__ __forceinline__ ushortT f2bf(float x) {
  union { float f; uint32_t u; } v; v.f = x;
  uint32_t r = v.u + 0x7fffu + ((v.u >> 16) & 1u);
  return (ushortT)(r >> 16);
}
__device__ __forceinline__ float bf2f(uint32_t b) {
  union { uint32_t u; float f; } v; v.u = b << 16;
  return v.f;
}
__device__ __forceinline__ void gll16(const void* g, void* l) {
  __builtin_amdgcn_global_load_lds((const __attribute__((address_space(1))) void*)g,
                                   (__attribute__((address_space(3))) void*)l, 16, 0, 0);
}
__device__ __forceinline__ void sbar() {
  asm volatile("" ::: "memory");
  __builtin_amdgcn_s_barrier();
  asm volatile("" ::: "memory");
}

// ---------------- transpose + fp32->bf16 convert: out[c][r] = in[r][c] ----------------
__global__ __launch_bounds__(256) void transpose_cvt(const float* __restrict__ in,
                                                     ushortT* __restrict__ out,
                                                     int in_rs, int out_rs) {
  __shared__ float tile[64][65];
  const int r0 = blockIdx.y * 64, c0 = blockIdx.x * 64;
  const int t = threadIdx.x, tc = (t & 15) * 4, tr = t >> 4;
#pragma unroll
  for (int p = 0; p < 4; ++p) {
    int r = tr + p * 16;
    float4 v = *(const float4*)&in[(size_t)(r0 + r) * in_rs + c0 + tc];
    tile[r][tc] = v.x; tile[r][tc + 1] = v.y; tile[r][tc + 2] = v.z; tile[r][tc + 3] = v.w;
  }
  __syncthreads();
#pragma unroll
  for (int p = 0; p < 4; ++p) {
    int r = tr + p * 16;
    ushort4 u;
    u.x = f2bf(tile[tc + 0][r]); u.y = f2bf(tile[tc + 1][r]);
    u.z = f2bf(tile[tc + 2][r]); u.w = f2bf(tile[tc + 3][r]);
    *(ushort4*)&out[(size_t)(c0 + r) * out_rs + r0 + tc] = u;
  }
}

// V transpose: vsrc fp32 [(b*S+s)*2048 + n*256 + d] -> vT bf16 [((b*8+n)*256 + d)*2048 + s]
__global__ __launch_bounds__(256) void vtrans(const float* __restrict__ vsrc,
                                              ushortT* __restrict__ vT) {
  __shared__ float tile[64][65];
  const int z = blockIdx.z, b = z >> 3, n = z & 7;
  const float* in = vsrc + (size_t)b * SEQ * (NKV * DH) + n * DH;
  ushortT* out = vT + (size_t)z * DH * SEQ;
  const int s0 = blockIdx.y * 64, d0 = blockIdx.x * 64;
  const int t = threadIdx.x, tc = (t & 15) * 4, tr = t >> 4;
#pragma unroll
  for (int p = 0; p < 4; ++p) {
    int r = tr + p * 16;
    float4 v = *(const float4*)&in[(size_t)(s0 + r) * (NKV * DH) + d0 + tc];
    tile[r][tc] = v.x; tile[r][tc + 1] = v.y; tile[r][tc + 2] = v.z; tile[r][tc + 3] = v.w;
  }
  __syncthreads();
#pragma unroll
  for (int p = 0; p < 4; ++p) {
    int r = tr + p * 16;
    ushort4 u;
    u.x = f2bf(tile[tc + 0][r]); u.y = f2bf(tile[tc + 1][r]);
    u.z = f2bf(tile[tc + 2][r]); u.w = f2bf(tile[tc + 3][r]);
    *(ushort4*)&out[(size_t)(d0 + r) * SEQ + s0 + tc] = u;
  }
}

// ---------------- RMSNorm family (448 threads, 8 cols/thread) ----------------
__device__ __forceinline__ float block_sum448(float v, float* sb) {
#pragma unroll
  for (int o = 32; o; o >>= 1) v += __shfl_xor(v, o, 64);
  __syncthreads();
  if ((threadIdx.x & 63) == 0) sb[threadIdx.x >> 6] = v;
  __syncthreads();
  float s = 0.f;
#pragma unroll
  for (int i = 0; i < 7; ++i) s += sb[i];
  return s;
}

__global__ __launch_bounds__(448) void rms_in(const float* __restrict__ in,
                                              const float* __restrict__ w,
                                              ushortT* __restrict__ out) {
  __shared__ float sb[8];
  const size_t row = blockIdx.x;
  const int c = threadIdx.x * 8;
  const float* p = in + row * HID + c;
  float4 a = *(const float4*)p, bq = *(const float4*)(p + 4);
  float v[8] = {a.x, a.y, a.z, a.w, bq.x, bq.y, bq.z, bq.w};
  float ssq = 0.f;
#pragma unroll
  for (int j = 0; j < 8; ++j) ssq += v[j] * v[j];
  float s = block_sum448(ssq, sb);
  float rs = rsqrtf(s * (1.0f / HID) + 1e-6f);
  uint32_t o[4];
#pragma unroll
  for (int j = 0; j < 4; ++j) {
    float r0 = v[2 * j] * rs * (1.f + w[c + 2 * j]);
    float r1 = v[2 * j + 1] * rs * (1.f + w[c + 2 * j + 1]);
    o[j] = (uint32_t)f2bf(r0) | ((uint32_t)f2bf(r1) << 16);
  }
  *(uint4*)(out + row * HID + c) = make_uint4(o[0], o[1], o[2], o[3]);
}

// NOTE: ao and resid alias (in-place in out_res) -> NO __restrict__ on them.
__global__ __launch_bounds__(448) void rms_add(const float* ao,
                                               const float* __restrict__ h,
                                               const float* __restrict__ w1,
                                               const float* __restrict__ w2,
                                               float* resid,
                                               ushortT* __restrict__ x2) {
  __shared__ float sb[8];
  const size_t row = blockIdx.x;
  const int c = threadIdx.x * 8;
  const float* p = ao + row * HID + c;
  float4 a = *(const float4*)p, bq = *(const float4*)(p + 4);
  float v[8] = {a.x, a.y, a.z, a.w, bq.x, bq.y, bq.z, bq.w};
  float ssq = 0.f;
#pragma unroll
  for (int j = 0; j < 8; ++j) ssq += v[j] * v[j];
  float s1 = block_sum448(ssq, sb);
  float rs1 = rsqrtf(s1 * (1.0f / HID) + 1e-6f);
  const float* hp = h + row * HID + c;
  float4 h0 = *(const float4*)hp, h1 = *(const float4*)(hp + 4);
  float hv[8] = {h0.x, h0.y, h0.z, h0.w, h1.x, h1.y, h1.z, h1.w};
  float r[8];
  float ssq2 = 0.f;
#pragma unroll
  for (int j = 0; j < 8; ++j) {
    r[j] = hv[j] + v[j] * rs1 * (1.f + w1[c + j]);
    ssq2 += r[j] * r[j];
  }
  float* rp = resid + row * HID + c;
  *(float4*)rp = make_float4(r[0], r[1], r[2], r[3]);
  *(float4*)(rp + 4) = make_float4(r[4], r[5], r[6], r[7]);
  float s2 = block_sum448(ssq2, sb);
  float rs2 = rsqrtf(s2 * (1.0f / HID) + 1e-6f);
  uint32_t o[4];
#pragma unroll
  for (int j = 0; j < 4; ++j) {
    float q0 = r[2 * j] * rs2 * (1.f + w2[c + 2 * j]);
    float q1 = r[2 * j + 1] * rs2 * (1.f + w2[c + 2 * j + 1]);
    o[j] = (uint32_t)f2bf(q0) | ((uint32_t)f2bf(q1) << 16);
  }
  *(uint4*)(x2 + row * HID + c) = make_uint4(o[0], o[1], o[2], o[3]);
}

// NOTE: in and out alias (in-place on out_x) -> NO __restrict__.
__global__ __launch_bounds__(448) void rms_out(const float* in,
                                               const float* __restrict__ w,
                                               float* out) {
  __shared__ float sb[8];
  const size_t row = blockIdx.x;
  const int c = threadIdx.x * 8;
  const float* p = in + row * HID + c;
  float4 a = *(const float4*)p, bq = *(const float4*)(p + 4);
  float v[8] = {a.x, a.y, a.z, a.w, bq.x, bq.y, bq.z, bq.w};
  float ssq = 0.f;
#pragma unroll
  for (int j = 0; j < 8; ++j) ssq += v[j] * v[j];
  float s = block_sum448(ssq, sb);
  float rs = rsqrtf(s * (1.0f / HID) + 1e-6f);
  float* op = out + row * HID + c;
  float r[8];
#pragma unroll
  for (int j = 0; j < 8; ++j) r[j] = v[j] * rs * (1.f + w[c + j]);
  *(float4*)op = make_float4(r[0], r[1], r[2], r[3]);
  *(float4*)(op + 4) = make_float4(r[4], r[5], r[6], r[7]);
}

// ---------------- RoPE (bf16 in) ----------------
__global__ __launch_bounds__(128) void rope_q_k(const ushortT* __restrict__ qraw,
                                                const int* __restrict__ pos,
                                                ushortT* __restrict__ qr) {
  const int s = blockIdx.x, h = blockIdx.y, b = blockIdx.z, i = threadIdx.x;
  float p = (float)pos[b * SEQ + s];
  float ang = p * exp2f(-(float)i * (13.287712379549449f / 128.f));
  float sn, cs;
  sincosf(ang, &sn, &cs);
  size_t ib = ((size_t)b * SEQ + s) * (NH * DH) + (size_t)h * DH + i;
  float x1 = bf2f(qraw[ib]), x2 = bf2f(qraw[ib + 128]);
  size_t ob = (((size_t)b * NH + h) * SEQ + s) * DH + i;
  qr[ob] = f2bf(x1 * cs - x2 * sn);
  qr[ob + 128] = f2bf(x2 * cs + x1 * sn);
}

__global__ __launch_bounds__(128) void rope_k_k(const ushortT* __restrict__ kraw,
                                                const int* __restrict__ pos,
                                                ushortT* __restrict__ kr,
                                                float* __restrict__ kv0) {
  const int s = blockIdx.x, n = blockIdx.y, b = blockIdx.z, i = threadIdx.x;
  float p = (float)pos[b * SEQ + s];
  float ang = p * exp2f(-(float)i * (13.287712379549449f / 128.f));
  float sn, cs;
  sincosf(ang, &sn, &cs);
  size_t ib = ((size_t)b * SEQ + s) * (NKV * DH) + (size_t)n * DH + i;
  float x1 = bf2f(kraw[ib]), x2 = bf2f(kraw[ib + 128]);
  float o1 = x1 * cs - x2 * sn, o2 = x2 * cs + x1 * sn;
  size_t ob = (((size_t)b * NKV + n) * SEQ + s) * DH + i;
  kr[ob] = f2bf(o1);
  kr[ob + 128] = f2bf(o2);
  size_t kb = (((size_t)b * SEQ + s) * NKV + n) * DH + i;
  kv0[kb] = o1;
  kv0[kb + 128] = o2;
}

// ---------------- 256x256 GEMM, BK=64, 8 waves, chunked counted-vmcnt pipeline --------
// C[M][N](op) = A[M][K](bf16,lda) * Bt[N][K](bf16,ldb)     [geometry identical to R3]
// LDS: 2 bufs x (A 256x64 = 32KB + B 256x64 = 32KB) = 128 KiB.
// Swizzle: 16B chunk c of row r at chunk c^(r&7); inverse-swz source, swz read (T2).
// 4 phases per K-tile: (mh,nh) quadrants, 16 MFMA each.
// Staging of tile t+1 split into chunk groups into the dead buffer:
//   q0: A rounds {0,2} (=A-mh0, 2 gll16) | q1: B rounds 0..3 (4) | q2: A rounds {1,3} (2)
// Counted gates (T4, never vmcnt(0) mid-loop):
//   before q0: vmcnt(2)+bar  -> certifies incoming tile's A-mh0 + all B (6 oldest)
//   before q2: vmcnt(6)+bar  -> certifies incoming tile's A-mh1 (keeps 6 newest flying)
// Per-wave count symmetry + barrier makes the per-wave vmcnt a block-wide certificate
// (m218). WAR safety: a wave issues stages only after the gate/phase barrier that
// follows every other wave's lgkmcnt(0) drain of the previous tile's reads.
template <int OUTMODE>  // 0=fp32 store, 1=bf16 store, 2=fp32 accum, 3=bf16 swiglu(up*gelu(G))
__global__ __launch_bounds__(512) void gemm256(const ushortT* __restrict__ A, int lda,
                                               const ushortT* __restrict__ Bt, int ldb,
                                               void* C, const ushortT* G,
                                               int N, int K) {
  __shared__ ushortT lds[65536];
  char* lb = (char*)lds;
  const int tid = threadIdx.x;
  // bijective XCD swizzle (all grids here are multiples of 8)
  const int nwg = gridDim.x * gridDim.y;
  const int lin = blockIdx.y * gridDim.x + blockIdx.x;
  const int cpx = nwg >> 3;
  const int lin2 = (lin & 7) * cpx + (lin >> 3);
  const int bx = lin2 % gridDim.x, by = lin2 / gridDim.x;
  const int m0 = by * 256, n0 = bx * 256;
  const int l = tid & 63, lr = l & 15, lg = l >> 4;
  const int wid = tid >> 6, wm2 = wid >> 2, wn4 = wid & 3;
  const int sr = tid >> 3, sc = tid & 7;  // staging: row-in-64, chunk 0..7

  f32x4 acc[8][4];
#pragma unroll
  for (int i = 0; i < 8; ++i)
#pragma unroll
    for (int j = 0; j < 4; ++j) acc[i][j] = (f32x4){0.f, 0.f, 0.f, 0.f};

  const int nt = K >> 6;
  const ushortT* Ag = A + (size_t)m0 * lda;
  const ushortT* Bg = Bt + (size_t)n0 * ldb;

  // stage A rounds {par, par+2} of K-tile tt into buffer d (rows par*64.., (par+2)*64..)
  auto stageA = [&](int tt, int par, char* dA) {
    const ushortT* g = Ag + (size_t)tt * 64;
#pragma unroll
    for (int rr = 0; rr < 2; ++rr) {
      int rnd = par + rr * 2;
      int row = rnd * 64 + sr;
      gll16((const char*)(g + (size_t)row * lda) + ((sc ^ (row & 7)) << 4),
            dA + rnd * 8192 + tid * 16);
    }
  };
  // stage all 4 B rounds of K-tile tt
  auto stageB = [&](int tt, char* dB) {
    const ushortT* g = Bg + (size_t)tt * 64;
#pragma unroll
    for (int rnd = 0; rnd < 4; ++rnd) {
      int row = rnd * 64 + sr;
      gll16((const char*)(g + (size_t)row * ldb) + ((sc ^ (row & 7)) << 4),
            dB + rnd * 8192 + tid * 16);
    }
  };
  short8 af[4][2], bf[2][2];
  auto rdA = [&](int mh, const char* Ab) {
#pragma unroll
    for (int i = 0; i < 4; ++i) {
      int r = wm2 * 128 + mh * 64 + i * 16 + lr;
#pragma unroll
      for (int ks = 0; ks < 2; ++ks)
        af[i][ks] = *(const short8*)(Ab + r * 128 + (((ks * 4 + lg) ^ (r & 7)) << 4));
    }
  };
  auto rdB = [&](int nh, const char* Bp) {
#pragma unroll
    for (int j = 0; j < 2; ++j) {
      int r = (wn4 & 1) * 64 + nh * 32 + j * 16 + lr;
#pragma unroll
      for (int ks = 0; ks < 2; ++ks)
        bf[j][ks] = *(const short8*)(Bp + r * 128 + (((ks * 4 + lg) ^ (r & 7)) << 4));
    }
  };
  auto phase_mm = [&](int mh, int nh) {
    sbar();
    asm volatile("s_waitcnt lgkmcnt(0)" ::: "memory");
    __builtin_amdgcn_sched_barrier(0);
    __builtin_amdgcn_s_setprio(1);
#pragma unroll
    for (int i = 0; i < 4; ++i)
#pragma unroll
      for (int j = 0; j < 2; ++j)
#pragma unroll
        for (int ks = 0; ks < 2; ++ks)
          acc[mh * 4 + i][nh * 2 + j] = __builtin_amdgcn_mfma_f32_16x16x32_bf16(
              af[i][ks], bf[j][ks], acc[mh * 4 + i][nh * 2 + j], 0, 0, 0);
    __builtin_amdgcn_s_setprio(0);
  };

  // prologue: stage tile 0 in gate-group order [A02, B0123, A13]
  stageA(0, 0, lb);
  stageB(0, lb + 32768);
  stageA(0, 1, lb);

  for (int t = 0; t < nt; ++t) {
    char* Ab = lb + (t & 1) * 65536;
    char* Bp = Ab + 32768 + ((wn4 >> 1) * 16384);
    char* nA = lb + ((t + 1) & 1) * 65536;
    char* nB = nA + 32768;
    const bool pf = (t + 1 < nt);
    // ---- q0: (mh0, nh0) ----
    asm volatile("s_waitcnt vmcnt(2)" ::: "memory");  // tile t: A-mh0 + B landed
    sbar();
    rdA(0, Ab);
    rdB(0, Bp);
    if (pf) stageA(t + 1, 0, nA);
    phase_mm(0, 0);
    // ---- q1: (mh0, nh1) ----
    rdB(1, Bp);
    if (pf) stageB(t + 1, nB);
    phase_mm(0, 1);
    // ---- q2: (mh1, nh0) ----
    if (pf) asm volatile("s_waitcnt vmcnt(6)" ::: "memory");  // tile t: A-mh1 landed
    else    asm volatile("s_waitcnt vmcnt(0)" ::: "memory");
    sbar();
    rdA(1, Ab);
    rdB(0, Bp);
    if (pf) stageA(t + 1, 1, nA);
    phase_mm(1, 0);
    // ---- q3: (mh1, nh1) ----
    rdB(1, Bp);
    phase_mm(1, 1);
  }
#pragma unroll
  for (int mi = 0; mi < 8; ++mi)
#pragma unroll
    for (int nj = 0; nj < 4; ++nj)
#pragma unroll
      for (int r = 0; r < 4; ++r) {
        size_t row = (size_t)(m0 + wm2 * 128 + mi * 16 + lg * 4 + r);
        size_t col = (size_t)(n0 + wn4 * 64 + nj * 16 + lr);
        size_t idx = row * N + col;
        if (OUTMODE == 0)
          ((float*)C)[idx] = acc[mi][nj][r];
        else if (OUTMODE == 1)
          ((ushortT*)C)[idx] = f2bf(acc[mi][nj][r]);
        else if (OUTMODE == 2)
          ((float*)C)[idx] += acc[mi][nj][r];
        else {
          float u = acc[mi][nj][r];
          float g = bf2f(G[idx]);
          float e = 0.5f * g * (1.f + tanhf(0.7978845608f * (g + 0.044715f * g * g * g)));
          ((ushortT*)C)[idx] = f2bf(u * e);
        }
      }
}

// ---------------- flash attention (sliding window 1024, causal, softcap 50) ----------------
__global__ __launch_bounds__(256) void attn_fwd(const ushortT* __restrict__ Q,   // [B][H][S][DH]
                                                const ushortT* __restrict__ Kk,  // [B][KV][S][DH]
                                                const ushortT* __restrict__ Vt,  // [B][KV][DH][S]
                                                ushortT* __restrict__ Out) {     // [B*S][H*DH]
  __shared__ ushortT Kl[32 * 256];
  __shared__ ushortT Vl[256 * 32];
  __shared__ ushortT Pl[4][16 * 32];
  const int tid = threadIdx.x;
  const int w = tid >> 6, l = tid & 63, lr = l & 15, lg = l >> 4;
  const int h = blockIdx.y, b = blockIdx.z;
  const int n = h >> 1;
  const int qs = blockIdx.x * 64;
  const int sw = qs + w * 16;

  const ushortT* qp = Q + (((size_t)b * NH + h) * SEQ + (sw + lr)) * DH;
  short8 qf[8];
#pragma unroll
  for (int kk = 0; kk < 8; ++kk) qf[kk] = *(const short8*)(qp + kk * 32 + lg * 8);

  f32x4 acc[16];
#pragma unroll
  for (int i = 0; i < 16; ++i) acc[i] = (f32x4){0.f, 0.f, 0.f, 0.f};
  float m_s = -1e30f, l_s = 0.f;

  const ushortT* Kbase = Kk + ((size_t)b * NKV + n) * SEQ * DH;
  const ushortT* Vbase = Vt + ((size_t)b * NKV + n) * DH * SEQ;

  int tlo = qs - (WINDOW - 1);
  if (tlo < 0) tlo = 0;
  const int t0b = tlo & ~31;
  const int nt = (qs + 64 - t0b) >> 5;
  const int scol = sw + lr;

  for (int it = 0; it < nt; ++it) {
    const int t0 = t0b + it * 32;
    __syncthreads();
    {
      const int rowk = tid >> 5;
      const int cbk = (tid & 31) * 16;
#pragma unroll
      for (int c = 0; c < 4; ++c) {
        int row = c * 8 + rowk;
        int cbs = cbk ^ ((row & 7) << 4);
        gll16((const char*)(Kbase + (size_t)(t0 + row) * DH) + cbs, (char*)Kl + c * 4096 + tid * 16);
      }
      const int rowv = tid >> 2;
      const int cbv = (tid & 3) * 16;
#pragma unroll
      for (int c = 0; c < 4; ++c) {
        int row = c * 64 + rowv;
        int cbs = cbv ^ ((row & 3) << 4);
        gll16((const char*)(Vbase + (size_t)row * SEQ + t0) + cbs, (char*)Vl + c * 4096 + tid * 16);
      }
    }
    __syncthreads();
    f32x4 st[2];
#pragma unroll
    for (int tt = 0; tt < 2; ++tt) {
      f32x4 a = (f32x4){0.f, 0.f, 0.f, 0.f};
      const int krow = tt * 16 + lr;
      const char* kb = (const char*)Kl + krow * 512;
      const int swz = (krow & 7) << 4;
#pragma unroll
      for (int kk = 0; kk < 8; ++kk) {
        short8 kf = *(const short8*)(kb + ((kk * 64 + lg * 16) ^ swz));
        a = __builtin_amdgcn_mfma_f32_16x16x32_bf16(kf, qf[kk], a, 0, 0, 0);
      }
      st[tt] = a;
    }
    float pvv[8];
    float tmax = -1e30f;
#pragma unroll
    for (int tt = 0; tt < 2; ++tt)
#pragma unroll
      for (int r = 0; r < 4; ++r) {
        int t = t0 + tt * 16 + lg * 4 + r;
        float x = st[tt][r] * 0.0625f;
        x = 50.f * tanhf(x * 0.02f);
        bool ok = (t <= scol) && (scol - t < WINDOW);
        x = ok ? x : -1e30f;
        pvv[tt * 4 + r] = x;
        tmax = fmaxf(tmax, x);
      }
    tmax = fmaxf(tmax, __shfl_xor(tmax, 16, 64));
    tmax = fmaxf(tmax, __shfl_xor(tmax, 32, 64));
    float mnew = fmaxf(m_s, tmax);
    float fsc = __expf(m_s - mnew);
    m_s = mnew;
    float tsum = 0.f;
#pragma unroll
    for (int i = 0; i < 8; ++i) {
      pvv[i] = __expf(pvv[i] - mnew);
      tsum += pvv[i];
    }
    tsum += __shfl_xor(tsum, 16, 64);
    tsum += __shfl_xor(tsum, 32, 64);
    l_s = l_s * fsc + tsum;
    {
      char* pb = (char*)&Pl[w][0] + lr * 64;
      const int pswz = (lr & 3) << 4;
#pragma unroll
      for (int tt = 0; tt < 2; ++tt) {
        uint32_t p01 = (uint32_t)f2bf(pvv[tt * 4 + 0]) | ((uint32_t)f2bf(pvv[tt * 4 + 1]) << 16);
        uint32_t p23 = (uint32_t)f2bf(pvv[tt * 4 + 2]) | ((uint32_t)f2bf(pvv[tt * 4 + 3]) << 16);
        *(uint32_t*)(pb + ((tt * 32 + lg * 8 + 0) ^ pswz)) = p01;
        *(uint32_t*)(pb + ((tt * 32 + lg * 8 + 4) ^ pswz)) = p23;
      }
    }
    float fr[4];
#pragma unroll
    for (int r = 0; r < 4; ++r) fr[r] = __shfl(fsc, lg * 4 + r, 64);
#pragma unroll
    for (int nd = 0; nd < 16; ++nd) {
      acc[nd][0] *= fr[0]; acc[nd][1] *= fr[1];
      acc[nd][2] *= fr[2]; acc[nd][3] *= fr[3];
    }
    const char* pfb = (const char*)&Pl[w][0] + lr * 64;
    short8 pf = *(const short8*)(pfb + ((lg * 16) ^ ((lr & 3) << 4)));
#pragma unroll
    for (int nd = 0; nd < 16; ++nd) {
      const int vrow = nd * 16 + lr;
      short8 vf = *(const short8*)((const char*)Vl + vrow * 64 + ((lg * 16) ^ ((vrow & 3) << 4)));
      acc[nd] = __builtin_amdgcn_mfma_f32_16x16x32_bf16(pf, vf, acc[nd], 0, 0, 0);
    }
  }
  float linv[4];
#pragma unroll
  for (int r = 0; r < 4; ++r) linv[r] = 1.f / __shfl(l_s, lg * 4 + r, 64);
#pragma unroll
  for (int nd = 0; nd < 16; ++nd)
#pragma unroll
    for (int r = 0; r < 4; ++r) {
      size_t row = (size_t)b * SEQ + sw + lg * 4 + r;
      Out[row * (NH * DH) + (size_t)h * DH + nd * 16 + lr] = f2bf(acc[nd][r] * linv[r]);
    }
}

// ---------------- host ----------------
extern "C" void kernel_launch(void* const* d_in, const int* in_sizes, int n_in,
                              void* d_out, int out_size, void* d_ws, size_t ws_size,
                              hipStream_t stream) {
  const float* hs = (const float*)d_in[0];
  const int* pos = (const int*)d_in[1];
  const float* w_in = (const float*)d_in[2];
  const float* w_pa = (const float*)d_in[3];
  const float* w_pf = (const float*)d_in[4];
  const float* w_po = (const float*)d_in[5];
  const float* qw = (const float*)d_in[6];
  const float* kw = (const float*)d_in[7];
  const float* vw = (const float*)d_in[8];
  const float* ow = (const float*)d_in[9];
  const float* gw = (const float*)d_in[10];
  const float* uw = (const float*)d_in[11];
  const float* dw = (const float*)d_in[12];

  float* out_x = (float*)d_out;
  float* out_res = out_x + (size_t)NTOK * HID;
  float* out_kv0 = out_res + (size_t)NTOK * HID;
  float* out_kv1 = out_kv0 + (size_t)NTOK * NKV * DH;

  char* ws = (char*)d_ws;
  // W region
  char* W = ws;
  ushortT* qwT = (ushortT*)(W);
  ushortT* kwT = (ushortT*)(W + 29360128);
  ushortT* vwT = (ushortT*)(W + 29360128 + 14680064);
  ushortT* owT = (ushortT*)(W + 29360128 + 2 * 14680064);
  ushortT* wS0 = (ushortT*)(W);              // 51,380,224 B
  ushortT* wS1 = (ushortT*)(W + 51380224);   // 51,380,224 B
  // R region
  char* R = ws + 102760448;
  ushortT* x1 = (ushortT*)(R);                           // 29,360,128
  ushortT* qraw_b = (ushortT*)(R + 29360128);            // 33,554,432 (A)
  ushortT* kraw_b = (ushortT*)(R + 62914560);            // 16,777,216 (B)
  ushortT* qrope = (ushortT*)(R + 79691776);             // 33,554,432 (C)
  ushortT* krope = (ushortT*)(R + 113246208);            // 16,777,216 (D)
  ushortT* vT = (ushortT*)(R + 130023424);               // 16,777,216 (E)
  ushortT* attnb = qraw_b;
  ushortT* x2 = x1;
  ushortT* gateC = (ushortT*)(R + 29360128);             // 58,720,256
  ushortT* upC = (ushortT*)(R + 29360128 + 58720256);    // (unused output; kept)
  ushortT* interC = gateC;
  float* attn_out = out_res;
  (void)upC;

  // --- phase 1: attention weights -> bf16 transposed ---
  transpose_cvt<<<dim3(4096 / 64, HID / 64), 256, 0, stream>>>(qw, qwT, 4096, HID);
  transpose_cvt<<<dim3(2048 / 64, HID / 64), 256, 0, stream>>>(kw, kwT, 2048, HID);
  transpose_cvt<<<dim3(2048 / 64, HID / 64), 256, 0, stream>>>(vw, vwT, 2048, HID);
  transpose_cvt<<<dim3(HID / 64, 4096 / 64), 256, 0, stream>>>(ow, owT, HID, 4096);

  // --- phase 2: input rmsnorm ---
  rms_in<<<NTOK, 448, 0, stream>>>(hs, w_in, x1);

  // --- phase 3: qkv projections (v -> out_kv1 fp32 directly) ---
  gemm256<1><<<dim3(16, 16), 512, 0, stream>>>(x1, HID, qwT, HID, qraw_b, nullptr, 4096, HID);
  gemm256<1><<<dim3(8, 16), 512, 0, stream>>>(x1, HID, kwT, HID, kraw_b, nullptr, 2048, HID);
  gemm256<0><<<dim3(8, 16), 512, 0, stream>>>(x1, HID, vwT, HID, out_kv1, nullptr, 2048, HID);

  // --- phase 4: rope (+kv_fused k out) + V transpose ---
  rope_q_k<<<dim3(SEQ, NH, NB), 128, 0, stream>>>(qraw_b, pos, qrope);
  rope_k_k<<<dim3(SEQ, NKV, NB), 128, 0, stream>>>(kraw_b, pos, krope, out_kv0);
  vtrans<<<dim3(DH / 64, SEQ / 64, NB * NKV), 256, 0, stream>>>(out_kv1, vT);

  // --- phase 5: attention ---
  attn_fwd<<<dim3(SEQ / 64, NH, NB), 256, 0, stream>>>(qrope, krope, vT, attnb);

  // --- phase 6: output projection (into out_res region) ---
  gemm256<0><<<dim3(HID / 256, 16), 512, 0, stream>>>(attnb, 4096, owT, 4096, attn_out, nullptr,
                                                      HID, 4096);

  // --- phase 7: post-attn norm + residual (in-place) + pre-ff norm ---
  rms_add<<<NTOK, 448, 0, stream>>>(attn_out, hs, w_pa, w_pf, out_res, x2);

  // --- phases 8-10: FFN in 2 chunks of 7168; swiglu fused in up-GEMM epilogue;
  //     down accumulates into out_x ---
  for (int c = 0; c < 2; ++c) {
    transpose_cvt<<<dim3(ICH / 64, HID / 64), 256, 0, stream>>>(gw + (size_t)c * ICH, wS0,
                                                                INTERDIM, HID);
    gemm256<1><<<dim3(ICH / 256, 16), 512, 0, stream>>>(x2, HID, wS0, HID, gateC, nullptr,
                                                        ICH, HID);
    transpose_cvt<<<dim3(ICH / 64, HID / 64), 256, 0, stream>>>(uw + (size_t)c * ICH, wS1,
                                                                INTERDIM, HID);
    // up-GEMM with fused swiglu epilogue: interC = up * gelu(gateC), in-place over gateC
    gemm256<3><<<dim3(ICH / 256, 16), 512, 0, stream>>>(x2, HID, wS1, HID, interC, gateC,
                                                        ICH, HID);
    transpose_cvt<<<dim3(HID / 64, ICH / 64), 256, 0, stream>>>(dw + (size_t)c * ICH * HID, wS0,
                                                                HID, ICH);
    if (c == 0)
      gemm256<0><<<dim3(HID / 256, 16), 512, 0, stream>>>(interC, ICH, wS0, ICH, out_x, nullptr,
                                                          HID, ICH);
    else
      gemm256<2><<<dim3(HID / 256, 16), 512, 0, stream>>>(interC, ICH, wS0, ICH, out_x, nullptr,
                                                          HID, ICH);
  }

  // --- phase 11: final norm (in-place on out_x) ---
  rms_out<<<NTOK, 448, 0, stream>>>(out_x, w_po, out_x);
}

// Round 7
// 2190.490 us; speedup vs baseline: 1.1221x; 1.0655x over previous
//
#include <hip/hip_runtime.h>
#include <stdint.h>

typedef unsigned short ushortT;
typedef float f32x4 __attribute__((ext_vector_type(4)));
typedef short short8 __attribute__((ext_vector_type(8)));

#define HID 3584
#define NH 16
#define NKV 8
#define DH 256
#define SEQ 2048
#define NB 2
#define NTOK 4096
#define INTERDIM 14336
#define ICH 7168  // FFN chunk of INTER
#define WINDOW 1024

__device__ __forceinline__ ushortT f2bf(float x) {
  union { float f; uint32_t u; } v; v.f = x;
  uint32_t r = v.u + 0x7fffu + ((v.u >> 16) & 1u);
  return (ushortT)(r >> 16);
}
__device__ __forceinline__ float bf2f(uint32_t b) {
  union { uint32_t u; float f; } v; v.u = b << 16;
  return v.f;
}
__device__ __forceinline__ void gll16(const void* g, void* l) {
  __builtin_amdgcn_global_load_lds((const __attribute__((address_space(1))) void*)g,
                                   (__attribute__((address_space(3))) void*)l, 16, 0, 0);
}
__device__ __forceinline__ void sbar() {
  asm volatile("" ::: "memory");
  __builtin_amdgcn_s_barrier();
  asm volatile("" ::: "memory");
}

// ---------------- transpose + fp32->bf16 convert: out[c][r] = in[r][c] ----------------
__global__ __launch_bounds__(256) void transpose_cvt(const float* __restrict__ in,
                                                     ushortT* __restrict__ out,
                                                     int in_rs, int out_rs) {
  __shared__ float tile[64][65];
  const int r0 = blockIdx.y * 64, c0 = blockIdx.x * 64;
  const int t = threadIdx.x, tc = (t & 15) * 4, tr = t >> 4;
#pragma unroll
  for (int p = 0; p < 4; ++p) {
    int r = tr + p * 16;
    float4 v = *(const float4*)&in[(size_t)(r0 + r) * in_rs + c0 + tc];
    tile[r][tc] = v.x; tile[r][tc + 1] = v.y; tile[r][tc + 2] = v.z; tile[r][tc + 3] = v.w;
  }
  __syncthreads();
#pragma unroll
  for (int p = 0; p < 4; ++p) {
    int r = tr + p * 16;
    ushort4 u;
    u.x = f2bf(tile[tc + 0][r]); u.y = f2bf(tile[tc + 1][r]);
    u.z = f2bf(tile[tc + 2][r]); u.w = f2bf(tile[tc + 3][r]);
    *(ushort4*)&out[(size_t)(c0 + r) * out_rs + r0 + tc] = u;
  }
}

// V transpose: vsrc fp32 [(b*S+s)*2048 + n*256 + d] -> vT bf16 [((b*8+n)*256 + d)*2048 + s]
__global__ __launch_bounds__(256) void vtrans(const float* __restrict__ vsrc,
                                              ushortT* __restrict__ vT) {
  __shared__ float tile[64][65];
  const int z = blockIdx.z, b = z >> 3, n = z & 7;
  const float* in = vsrc + (size_t)b * SEQ * (NKV * DH) + n * DH;
  ushortT* out = vT + (size_t)z * DH * SEQ;
  const int s0 = blockIdx.y * 64, d0 = blockIdx.x * 64;
  const int t = threadIdx.x, tc = (t & 15) * 4, tr = t >> 4;
#pragma unroll
  for (int p = 0; p < 4; ++p) {
    int r = tr + p * 16;
    float4 v = *(const float4*)&in[(size_t)(s0 + r) * (NKV * DH) + d0 + tc];
    tile[r][tc] = v.x; tile[r][tc + 1] = v.y; tile[r][tc + 2] = v.z; tile[r][tc + 3] = v.w;
  }
  __syncthreads();
#pragma unroll
  for (int p = 0; p < 4; ++p) {
    int r = tr + p * 16;
    ushort4 u;
    u.x = f2bf(tile[tc + 0][r]); u.y = f2bf(tile[tc + 1][r]);
    u.z = f2bf(tile[tc + 2][r]); u.w = f2bf(tile[tc + 3][r]);
    *(ushort4*)&out[(size_t)(d0 + r) * SEQ + s0 + tc] = u;
  }
}

// ---------------- RMSNorm family (448 threads, 8 cols/thread) ----------------
__device__ __forceinline__ float block_sum448(float v, float* sb) {
#pragma unroll
  for (int o = 32; o; o >>= 1) v += __shfl_xor(v, o, 64);
  __syncthreads();
  if ((threadIdx.x & 63) == 0) sb[threadIdx.x >> 6] = v;
  __syncthreads();
  float s = 0.f;
#pragma unroll
  for (int i = 0; i < 7; ++i) s += sb[i];
  return s;
}

__global__ __launch_bounds__(448) void rms_in(const float* __restrict__ in,
                                              const float* __restrict__ w,
                                              ushortT* __restrict__ out) {
  __shared__ float sb[8];
  const size_t row = blockIdx.x;
  const int c = threadIdx.x * 8;
  const float* p = in + row * HID + c;
  float4 a = *(const float4*)p, bq = *(const float4*)(p + 4);
  float v[8] = {a.x, a.y, a.z, a.w, bq.x, bq.y, bq.z, bq.w};
  float ssq = 0.f;
#pragma unroll
  for (int j = 0; j < 8; ++j) ssq += v[j] * v[j];
  float s = block_sum448(ssq, sb);
  float rs = rsqrtf(s * (1.0f / HID) + 1e-6f);
  uint32_t o[4];
#pragma unroll
  for (int j = 0; j < 4; ++j) {
    float r0 = v[2 * j] * rs * (1.f + w[c + 2 * j]);
    float r1 = v[2 * j + 1] * rs * (1.f + w[c + 2 * j + 1]);
    o[j] = (uint32_t)f2bf(r0) | ((uint32_t)f2bf(r1) << 16);
  }
  *(uint4*)(out + row * HID + c) = make_uint4(o[0], o[1], o[2], o[3]);
}

// NOTE: ao and resid alias (in-place in out_res) -> NO __restrict__ on them.
__global__ __launch_bounds__(448) void rms_add(const float* ao,
                                               const float* __restrict__ h,
                                               const float* __restrict__ w1,
                                               const float* __restrict__ w2,
                                               float* resid,
                                               ushortT* __restrict__ x2) {
  __shared__ float sb[8];
  const size_t row = blockIdx.x;
  const int c = threadIdx.x * 8;
  const float* p = ao + row * HID + c;
  float4 a = *(const float4*)p, bq = *(const float4*)(p + 4);
  float v[8] = {a.x, a.y, a.z, a.w, bq.x, bq.y, bq.z, bq.w};
  float ssq = 0.f;
#pragma unroll
  for (int j = 0; j < 8; ++j) ssq += v[j] * v[j];
  float s1 = block_sum448(ssq, sb);
  float rs1 = rsqrtf(s1 * (1.0f / HID) + 1e-6f);
  const float* hp = h + row * HID + c;
  float4 h0 = *(const float4*)hp, h1 = *(const float4*)(hp + 4);
  float hv[8] = {h0.x, h0.y, h0.z, h0.w, h1.x, h1.y, h1.z, h1.w};
  float r[8];
  float ssq2 = 0.f;
#pragma unroll
  for (int j = 0; j < 8; ++j) {
    r[j] = hv[j] + v[j] * rs1 * (1.f + w1[c + j]);
    ssq2 += r[j] * r[j];
  }
  float* rp = resid + row * HID + c;
  *(float4*)rp = make_float4(r[0], r[1], r[2], r[3]);
  *(float4*)(rp + 4) = make_float4(r[4], r[5], r[6], r[7]);
  float s2 = block_sum448(ssq2, sb);
  float rs2 = rsqrtf(s2 * (1.0f / HID) + 1e-6f);
  uint32_t o[4];
#pragma unroll
  for (int j = 0; j < 4; ++j) {
    float q0 = r[2 * j] * rs2 * (1.f + w2[c + 2 * j]);
    float q1 = r[2 * j + 1] * rs2 * (1.f + w2[c + 2 * j + 1]);
    o[j] = (uint32_t)f2bf(q0) | ((uint32_t)f2bf(q1) << 16);
  }
  *(uint4*)(x2 + row * HID + c) = make_uint4(o[0], o[1], o[2], o[3]);
}

// NOTE: in and out alias (in-place on out_x) -> NO __restrict__.
__global__ __launch_bounds__(448) void rms_out(const float* in,
                                               const float* __restrict__ w,
                                               float* out) {
  __shared__ float sb[8];
  const size_t row = blockIdx.x;
  const int c = threadIdx.x * 8;
  const float* p = in + row * HID + c;
  float4 a = *(const float4*)p, bq = *(const float4*)(p + 4);
  float v[8] = {a.x, a.y, a.z, a.w, bq.x, bq.y, bq.z, bq.w};
  float ssq = 0.f;
#pragma unroll
  for (int j = 0; j < 8; ++j) ssq += v[j] * v[j];
  float s = block_sum448(ssq, sb);
  float rs = rsqrtf(s * (1.0f / HID) + 1e-6f);
  float* op = out + row * HID + c;
  float r[8];
#pragma unroll
  for (int j = 0; j < 8; ++j) r[j] = v[j] * rs * (1.f + w[c + j]);
  *(float4*)op = make_float4(r[0], r[1], r[2], r[3]);
  *(float4*)(op + 4) = make_float4(r[4], r[5], r[6], r[7]);
}

// ---------------- RoPE (bf16 in) ----------------
__global__ __launch_bounds__(128) void rope_q_k(const ushortT* __restrict__ qraw,
                                                const int* __restrict__ pos,
                                                ushortT* __restrict__ qr) {
  const int s = blockIdx.x, h = blockIdx.y, b = blockIdx.z, i = threadIdx.x;
  float p = (float)pos[b * SEQ + s];
  float ang = p * exp2f(-(float)i * (13.287712379549449f / 128.f));
  float sn, cs;
  sincosf(ang, &sn, &cs);
  size_t ib = ((size_t)b * SEQ + s) * (NH * DH) + (size_t)h * DH + i;
  float x1 = bf2f(qraw[ib]), x2 = bf2f(qraw[ib + 128]);
  size_t ob = (((size_t)b * NH + h) * SEQ + s) * DH + i;
  qr[ob] = f2bf(x1 * cs - x2 * sn);
  qr[ob + 128] = f2bf(x2 * cs + x1 * sn);
}

__global__ __launch_bounds__(128) void rope_k_k(const ushortT* __restrict__ kraw,
                                                const int* __restrict__ pos,
                                                ushortT* __restrict__ kr,
                                                float* __restrict__ kv0) {
  const int s = blockIdx.x, n = blockIdx.y, b = blockIdx.z, i = threadIdx.x;
  float p = (float)pos[b * SEQ + s];
  float ang = p * exp2f(-(float)i * (13.287712379549449f / 128.f));
  float sn, cs;
  sincosf(ang, &sn, &cs);
  size_t ib = ((size_t)b * SEQ + s) * (NKV * DH) + (size_t)n * DH + i;
  float x1 = bf2f(kraw[ib]), x2 = bf2f(kraw[ib + 128]);
  float o1 = x1 * cs - x2 * sn, o2 = x2 * cs + x1 * sn;
  size_t ob = (((size_t)b * NKV + n) * SEQ + s) * DH + i;
  kr[ob] = f2bf(o1);
  kr[ob + 128] = f2bf(o2);
  size_t kb = (((size_t)b * SEQ + s) * NKV + n) * DH + i;
  kv0[kb] = o1;
  kv0[kb + 128] = o2;
}

// ------------- 256x256 GEMM, m201-style 8-phase / 2-K-tile iteration -------------
// C[M][N](op) = A[M][K](bf16,lda) * Bt[N][K](bf16,ldb)
// LDS 128 KiB: buf0 (even K-tiles) / buf1 (odd), each 64KB = [A-h0|A-h1|B-h0|B-h1] x16KB.
// 8 waves (2M x 4N): wave (wm,wn) owns rows wm*128+..127, cols wn*64+..63; reads only
// A-half wm and B-half wn>>1. Quadrant phase (mh,nh) = 16 MFMA (4 m-frag x 2 n-frag x 2 ks).
// Iter i: P1-P4 compute T0=2i (buf0), P5-P8 compute T1=2i+1 (buf1).
// Stage slots (1 half-tile = 2 gll16 per phase, into region freed by prior reads):
//   P1: T1.A-h1 (i>0)  P2: T1.B-h1 (i>0)  P3: S0.B-h0  P4: S0.A-h0
//   P5: S0.A-h1        P6: S0.B-h1        P7: S1.B-h0  P8: S1.A-h0   (S0=2i+2, S1=2i+3)
// Gates (counted; vmcnt(0) only in tail iter):
//   end P4: vmcnt(4) -> certifies T1 (4 oldest half-tiles), leaves S0.{Bh0,Ah0} in flight
//   end P8: vmcnt(4) -> certifies S0 (next iter's T0), leaves S1.{Bh0,Ah0} in flight
// Phase: {ds-reads; stage; [lgkmcnt(8) if 12 reads]; barrier; lgkmcnt(0)+sched_barrier(0);
//         setprio(1); 16 MFMA; setprio(0); [gate]; barrier}   (nt = K/64 even: 56/64/112)
template <int OUTMODE>  // 0=fp32 store, 1=bf16 store, 2=fp32 accumulate
__global__ __launch_bounds__(512) void gemm8p(const ushortT* __restrict__ A, int lda,
                                              const ushortT* __restrict__ Bt, int ldb,
                                              void* __restrict__ C, int N, int K) {
  __shared__ ushortT lds[65536];
  char* lb = (char*)lds;
  const int tid = threadIdx.x;
  // bijective XCD swizzle (all grids here are multiples of 8)
  const int nwg = gridDim.x * gridDim.y;
  const int lin = blockIdx.y * gridDim.x + blockIdx.x;
  const int cpx = nwg >> 3;
  const int lin2 = (lin & 7) * cpx + (lin >> 3);
  const int bx = lin2 % gridDim.x, by = lin2 / gridDim.x;
  const int m0 = by * 256, n0 = bx * 256;
  const int l = tid & 63, lr = l & 15, lg = l >> 4;
  const int wid = tid >> 6, wm = wid >> 2, wn = wid & 3;
  const int sr = tid >> 3, sc = tid & 7;

  f32x4 acc[8][4];
#pragma unroll
  for (int i = 0; i < 8; ++i)
#pragma unroll
    for (int j = 0; j < 4; ++j) acc[i][j] = (f32x4){0.f, 0.f, 0.f, 0.f};

  const int nt = K >> 6;
  const ushortT* Ag = A + (size_t)m0 * lda;
  const ushortT* Bg = Bt + (size_t)n0 * ldb;

  // stage one half-tile (2 x gll16): op 0=A 1=B, half h, K-tile tt -> buf (tt&1)
  auto stHT = [&](int tt, int op, int h) {
    char* dst = lb + (tt & 1) * 65536 + op * 32768 + h * 16384;
    const ushortT* g = (op ? Bg : Ag) + (size_t)tt * 64;
    const int ld = op ? ldb : lda;
#pragma unroll
    for (int L = 0; L < 2; ++L) {
      int row = h * 128 + L * 64 + sr;
      gll16((const char*)(g + (size_t)row * ld) + ((sc ^ (row & 7)) << 4),
            dst + L * 8192 + tid * 16);
    }
  };
  short8 afA[4][2], bfA[2][2], bfB[2][2];
  auto rdA = [&](const char* buf, int mh) {
#pragma unroll
    for (int i4 = 0; i4 < 4; ++i4) {
      int r = wm * 128 + mh * 64 + i4 * 16 + lr;
      const char* base = buf + wm * 16384 + (r & 127) * 128;
#pragma unroll
      for (int ks = 0; ks < 2; ++ks)
        afA[i4][ks] = *(const short8*)(base + (((ks * 4 + lg) ^ (r & 7)) << 4));
    }
  };
  auto rdB = [&](const char* buf, int nh, short8 (*bf)[2]) {
#pragma unroll
    for (int j = 0; j < 2; ++j) {
      int r = wn * 64 + nh * 32 + j * 16 + lr;
      const char* base = buf + 32768 + (wn >> 1) * 16384 + (r & 127) * 128;
#pragma unroll
      for (int ks = 0; ks < 2; ++ks)
        bf[j][ks] = *(const short8*)(base + (((ks * 4 + lg) ^ (r & 7)) << 4));
    }
  };
  auto mid = [&]() {
    sbar();
    asm volatile("s_waitcnt lgkmcnt(0)" ::: "memory");
    __builtin_amdgcn_sched_barrier(0);
  };
  auto mm = [&](int mh, int nh, short8 (*bf)[2]) {
    __builtin_amdgcn_s_setprio(1);
#pragma unroll
    for (int i4 = 0; i4 < 4; ++i4)
#pragma unroll
      for (int j = 0; j < 2; ++j)
#pragma unroll
        for (int ks = 0; ks < 2; ++ks)
          acc[mh * 4 + i4][nh * 2 + j] = __builtin_amdgcn_mfma_f32_16x16x32_bf16(
              afA[i4][ks], bf[j][ks], acc[mh * 4 + i4][nh * 2 + j], 0, 0, 0);
    __builtin_amdgcn_s_setprio(0);
  };

  // prologue: tiles 0 (buf0) and 1 (buf1) fully; certify tile 0, leave tile 1 in flight
  stHT(0, 0, 0); stHT(0, 0, 1); stHT(0, 1, 0); stHT(0, 1, 1);
  stHT(1, 0, 0); stHT(1, 0, 1); stHT(1, 1, 0); stHT(1, 1, 1);
  asm volatile("s_waitcnt vmcnt(8)" ::: "memory");
  sbar();

  const int nit = nt >> 1;
  const char* b0 = lb;
  const char* b1 = lb + 65536;
  for (int i = 0; i < nit; ++i) {
    const int t1 = 2 * i + 1, s0 = 2 * i + 2, s1 = 2 * i + 3;
    const bool hs0 = s0 < nt, hs1 = s1 < nt, pre = i > 0;
    // ---- P1: T0 (0,0) ----
    rdA(b0, 0);
    rdB(b0, 0, bfA);
    if (pre) stHT(t1, 0, 1);
    asm volatile("s_waitcnt lgkmcnt(8)" ::: "memory");
    mid(); mm(0, 0, bfA); sbar();
    // ---- P2: T0 (0,1) ----
    rdB(b0, 1, bfB);
    if (pre) stHT(t1, 1, 1);
    mid(); mm(0, 1, bfB); sbar();
    // ---- P3: T0 (1,0) ----
    rdA(b0, 1);
    if (hs0) stHT(s0, 1, 0);
    mid(); mm(1, 0, bfA); sbar();
    // ---- P4: T0 (1,1) + gate A ----
    if (hs0) stHT(s0, 0, 0);
    mid(); mm(1, 1, bfB);
    if (hs0) asm volatile("s_waitcnt vmcnt(4)" ::: "memory");
    else     asm volatile("s_waitcnt vmcnt(0)" ::: "memory");
    sbar();
    // ---- P5: T1 (0,0) ----
    rdA(b1, 0);
    rdB(b1, 0, bfA);
    if (hs0) stHT(s0, 0, 1);
    asm volatile("s_waitcnt lgkmcnt(8)" ::: "memory");
    mid(); mm(0, 0, bfA); sbar();
    // ---- P6: T1 (0,1) ----
    rdB(b1, 1, bfB);
    if (hs0) stHT(s0, 1, 1);
    mid(); mm(0, 1, bfB); sbar();
    // ---- P7: T1 (1,0) ----
    rdA(b1, 1);
    if (hs1) stHT(s1, 1, 0);
    mid(); mm(1, 0, bfA); sbar();
    // ---- P8: T1 (1,1) + gate B ----
    if (hs1) stHT(s1, 0, 0);
    mid(); mm(1, 1, bfB);
    if (hs1) asm volatile("s_waitcnt vmcnt(4)" ::: "memory");
    sbar();
  }
#pragma unroll
  for (int mi = 0; mi < 8; ++mi)
#pragma unroll
    for (int nj = 0; nj < 4; ++nj)
#pragma unroll
      for (int r = 0; r < 4; ++r) {
        size_t row = (size_t)(m0 + wm * 128 + mi * 16 + lg * 4 + r);
        size_t col = (size_t)(n0 + wn * 64 + nj * 16 + lr);
        size_t idx = row * N + col;
        if (OUTMODE == 0)
          ((float*)C)[idx] = acc[mi][nj][r];
        else if (OUTMODE == 1)
          ((ushortT*)C)[idx] = f2bf(acc[mi][nj][r]);
        else
          ((float*)C)[idx] += acc[mi][nj][r];
      }
}

// ---------------- swiglu: o = up * gelu_tanh(gate), all bf16 ----------------
__global__ __launch_bounds__(256) void swiglu_k(const ushortT* __restrict__ g,
                                                const ushortT* __restrict__ u,
                                                ushortT* __restrict__ o, int n16) {
  int i = blockIdx.x * 256 + threadIdx.x;
  if (i >= n16) return;
  uint4 gv = ((const uint4*)g)[i];
  uint4 uv = ((const uint4*)u)[i];
  uint32_t ga[4] = {gv.x, gv.y, gv.z, gv.w};
  uint32_t ua[4] = {uv.x, uv.y, uv.z, uv.w};
  uint32_t rr[4];
#pragma unroll
  for (int j = 0; j < 4; ++j) {
    float g0 = bf2f(ga[j] & 0xffffu), g1 = bf2f(ga[j] >> 16);
    float u0 = bf2f(ua[j] & 0xffffu), u1 = bf2f(ua[j] >> 16);
    float e0 = 0.5f * g0 * (1.f + tanhf(0.7978845608f * (g0 + 0.044715f * g0 * g0 * g0)));
    float e1 = 0.5f * g1 * (1.f + tanhf(0.7978845608f * (g1 + 0.044715f * g1 * g1 * g1)));
    rr[j] = (uint32_t)f2bf(u0 * e0) | ((uint32_t)f2bf(u1 * e1) << 16);
  }
  ((uint4*)o)[i] = make_uint4(rr[0], rr[1], rr[2], rr[3]);
}

// ---------------- flash attention (sliding window 1024, causal, softcap 50) ----------------
__global__ __launch_bounds__(256) void attn_fwd(const ushortT* __restrict__ Q,   // [B][H][S][DH]
                                                const ushortT* __restrict__ Kk,  // [B][KV][S][DH]
                                                const ushortT* __restrict__ Vt,  // [B][KV][DH][S]
                                                ushortT* __restrict__ Out) {     // [B*S][H*DH]
  __shared__ ushortT Kl[32 * 256];
  __shared__ ushortT Vl[256 * 32];
  __shared__ ushortT Pl[4][16 * 32];
  const int tid = threadIdx.x;
  const int w = tid >> 6, l = tid & 63, lr = l & 15, lg = l >> 4;
  const int h = blockIdx.y, b = blockIdx.z;
  const int n = h >> 1;
  const int qs = blockIdx.x * 64;
  const int sw = qs + w * 16;

  const ushortT* qp = Q + (((size_t)b * NH + h) * SEQ + (sw + lr)) * DH;
  short8 qf[8];
#pragma unroll
  for (int kk = 0; kk < 8; ++kk) qf[kk] = *(const short8*)(qp + kk * 32 + lg * 8);

  f32x4 acc[16];
#pragma unroll
  for (int i = 0; i < 16; ++i) acc[i] = (f32x4){0.f, 0.f, 0.f, 0.f};
  float m_s = -1e30f, l_s = 0.f;

  const ushortT* Kbase = Kk + ((size_t)b * NKV + n) * SEQ * DH;
  const ushortT* Vbase = Vt + ((size_t)b * NKV + n) * DH * SEQ;

  int tlo = qs - (WINDOW - 1);
  if (tlo < 0) tlo = 0;
  const int t0b = tlo & ~31;
  const int nt = (qs + 64 - t0b) >> 5;
  const int scol = sw + lr;

  for (int it = 0; it < nt; ++it) {
    const int t0 = t0b + it * 32;
    __syncthreads();
    {
      const int rowk = tid >> 5;
      const int cbk = (tid & 31) * 16;
#pragma unroll
      for (int c = 0; c < 4; ++c) {
        int row = c * 8 + rowk;
        int cbs = cbk ^ ((row & 7) << 4);
        gll16((const char*)(Kbase + (size_t)(t0 + row) * DH) + cbs, (char*)Kl + c * 4096 + tid * 16);
      }
      const int rowv = tid >> 2;
      const int cbv = (tid & 3) * 16;
#pragma unroll
      for (int c = 0; c < 4; ++c) {
        int row = c * 64 + rowv;
        int cbs = cbv ^ ((row & 3) << 4);
        gll16((const char*)(Vbase + (size_t)row * SEQ + t0) + cbs, (char*)Vl + c * 4096 + tid * 16);
      }
    }
    __syncthreads();
    f32x4 st[2];
#pragma unroll
    for (int tt = 0; tt < 2; ++tt) {
      f32x4 a = (f32x4){0.f, 0.f, 0.f, 0.f};
      const int krow = tt * 16 + lr;
      const char* kb = (const char*)Kl + krow * 512;
      const int swz = (krow & 7) << 4;
#pragma unroll
      for (int kk = 0; kk < 8; ++kk) {
        short8 kf = *(const short8*)(kb + ((kk * 64 + lg * 16) ^ swz));
        a = __builtin_amdgcn_mfma_f32_16x16x32_bf16(kf, qf[kk], a, 0, 0, 0);
      }
      st[tt] = a;
    }
    float pvv[8];
    float tmax = -1e30f;
#pragma unroll
    for (int tt = 0; tt < 2; ++tt)
#pragma unroll
      for (int r = 0; r < 4; ++r) {
        int t = t0 + tt * 16 + lg * 4 + r;
        float x = st[tt][r] * 0.0625f;
        x = 50.f * tanhf(x * 0.02f);
        bool ok = (t <= scol) && (scol - t < WINDOW);
        x = ok ? x : -1e30f;
        pvv[tt * 4 + r] = x;
        tmax = fmaxf(tmax, x);
      }
    tmax = fmaxf(tmax, __shfl_xor(tmax, 16, 64));
    tmax = fmaxf(tmax, __shfl_xor(tmax, 32, 64));
    float mnew = fmaxf(m_s, tmax);
    float fsc = __expf(m_s - mnew);
    m_s = mnew;
    float tsum = 0.f;
#pragma unroll
    for (int i = 0; i < 8; ++i) {
      pvv[i] = __expf(pvv[i] - mnew);
      tsum += pvv[i];
    }
    tsum += __shfl_xor(tsum, 16, 64);
    tsum += __shfl_xor(tsum, 32, 64);
    l_s = l_s * fsc + tsum;
    {
      char* pb = (char*)&Pl[w][0] + lr * 64;
      const int pswz = (lr & 3) << 4;
#pragma unroll
      for (int tt = 0; tt < 2; ++tt) {
        uint32_t p01 = (uint32_t)f2bf(pvv[tt * 4 + 0]) | ((uint32_t)f2bf(pvv[tt * 4 + 1]) << 16);
        uint32_t p23 = (uint32_t)f2bf(pvv[tt * 4 + 2]) | ((uint32_t)f2bf(pvv[tt * 4 + 3]) << 16);
        *(uint32_t*)(pb + ((tt * 32 + lg * 8 + 0) ^ pswz)) = p01;
        *(uint32_t*)(pb + ((tt * 32 + lg * 8 + 4) ^ pswz)) = p23;
      }
    }
    float fr[4];
#pragma unroll
    for (int r = 0; r < 4; ++r) fr[r] = __shfl(fsc, lg * 4 + r, 64);
#pragma unroll
    for (int nd = 0; nd < 16; ++nd) {
      acc[nd][0] *= fr[0]; acc[nd][1] *= fr[1];
      acc[nd][2] *= fr[2]; acc[nd][3] *= fr[3];
    }
    const char* pfb = (const char*)&Pl[w][0] + lr * 64;
    short8 pf = *(const short8*)(pfb + ((lg * 16) ^ ((lr & 3) << 4)));
#pragma unroll
    for (int nd = 0; nd < 16; ++nd) {
      const int vrow = nd * 16 + lr;
      short8 vf = *(const short8*)((const char*)Vl + vrow * 64 + ((lg * 16) ^ ((vrow & 3) << 4)));
      acc[nd] = __builtin_amdgcn_mfma_f32_16x16x32_bf16(pf, vf, acc[nd], 0, 0, 0);
    }
  }
  float linv[4];
#pragma unroll
  for (int r = 0; r < 4; ++r) linv[r] = 1.f / __shfl(l_s, lg * 4 + r, 64);
#pragma unroll
  for (int nd = 0; nd < 16; ++nd)
#pragma unroll
    for (int r = 0; r < 4; ++r) {
      size_t row = (size_t)b * SEQ + sw + lg * 4 + r;
      Out[row * (NH * DH) + (size_t)h * DH + nd * 16 + lr] = f2bf(acc[nd][r] * linv[r]);
    }
}

// ---------------- host ----------------
extern "C" void kernel_launch(void* const* d_in, const int* in_sizes, int n_in,
                              void* d_out, int out_size, void* d_ws, size_t ws_size,
                              hipStream_t stream) {
  const float* hs = (const float*)d_in[0];
  const int* pos = (const int*)d_in[1];
  const float* w_in = (const float*)d_in[2];
  const float* w_pa = (const float*)d_in[3];
  const float* w_pf = (const float*)d_in[4];
  const float* w_po = (const float*)d_in[5];
  const float* qw = (const float*)d_in[6];
  const float* kw = (const float*)d_in[7];
  const float* vw = (const float*)d_in[8];
  const float* ow = (const float*)d_in[9];
  const float* gw = (const float*)d_in[10];
  const float* uw = (const float*)d_in[11];
  const float* dw = (const float*)d_in[12];

  float* out_x = (float*)d_out;
  float* out_res = out_x + (size_t)NTOK * HID;
  float* out_kv0 = out_res + (size_t)NTOK * HID;
  float* out_kv1 = out_kv0 + (size_t)NTOK * NKV * DH;

  char* ws = (char*)d_ws;
  // W region
  char* W = ws;
  ushortT* qwT = (ushortT*)(W);
  ushortT* kwT = (ushortT*)(W + 29360128);
  ushortT* vwT = (ushortT*)(W + 29360128 + 14680064);
  ushortT* owT = (ushortT*)(W + 29360128 + 2 * 14680064);
  ushortT* wS0 = (ushortT*)(W);              // 51,380,224 B
  ushortT* wS1 = (ushortT*)(W + 51380224);   // 51,380,224 B
  // R region
  char* R = ws + 102760448;
  ushortT* x1 = (ushortT*)(R);                           // 29,360,128
  ushortT* qraw_b = (ushortT*)(R + 29360128);            // 33,554,432 (A)
  ushortT* kraw_b = (ushortT*)(R + 62914560);            // 16,777,216 (B)
  ushortT* qrope = (ushortT*)(R + 79691776);             // 33,554,432 (C)
  ushortT* krope = (ushortT*)(R + 113246208);            // 16,777,216 (D)
  ushortT* vT = (ushortT*)(R + 130023424);               // 16,777,216 (E)
  ushortT* attnb = qraw_b;
  ushortT* x2 = x1;
  ushortT* gateC = (ushortT*)(R + 29360128);             // 58,720,256
  ushortT* upC = (ushortT*)(R + 29360128 + 58720256);    // 58,720,256
  ushortT* interC = gateC;
  float* attn_out = out_res;

  // --- phase 1: attention weights -> bf16 transposed ---
  transpose_cvt<<<dim3(4096 / 64, HID / 64), 256, 0, stream>>>(qw, qwT, 4096, HID);
  transpose_cvt<<<dim3(2048 / 64, HID / 64), 256, 0, stream>>>(kw, kwT, 2048, HID);
  transpose_cvt<<<dim3(2048 / 64, HID / 64), 256, 0, stream>>>(vw, vwT, 2048, HID);
  transpose_cvt<<<dim3(HID / 64, 4096 / 64), 256, 0, stream>>>(ow, owT, HID, 4096);

  // --- phase 2: input rmsnorm ---
  rms_in<<<NTOK, 448, 0, stream>>>(hs, w_in, x1);

  // --- phase 3: qkv projections (v -> out_kv1 fp32 directly) ---
  gemm8p<1><<<dim3(16, 16), 512, 0, stream>>>(x1, HID, qwT, HID, qraw_b, 4096, HID);
  gemm8p<1><<<dim3(8, 16), 512, 0, stream>>>(x1, HID, kwT, HID, kraw_b, 2048, HID);
  gemm8p<0><<<dim3(8, 16), 512, 0, stream>>>(x1, HID, vwT, HID, out_kv1, 2048, HID);

  // --- phase 4: rope (+kv_fused k out) + V transpose ---
  rope_q_k<<<dim3(SEQ, NH, NB), 128, 0, stream>>>(qraw_b, pos, qrope);
  rope_k_k<<<dim3(SEQ, NKV, NB), 128, 0, stream>>>(kraw_b, pos, krope, out_kv0);
  vtrans<<<dim3(DH / 64, SEQ / 64, NB * NKV), 256, 0, stream>>>(out_kv1, vT);

  // --- phase 5: attention ---
  attn_fwd<<<dim3(SEQ / 64, NH, NB), 256, 0, stream>>>(qrope, krope, vT, attnb);

  // --- phase 6: output projection (into out_res region) ---
  gemm8p<0><<<dim3(HID / 256, 16), 512, 0, stream>>>(attnb, 4096, owT, 4096, attn_out, HID, 4096);

  // --- phase 7: post-attn norm + residual (in-place) + pre-ff norm ---
  rms_add<<<NTOK, 448, 0, stream>>>(attn_out, hs, w_pa, w_pf, out_res, x2);

  // --- phases 8-10: FFN in 2 chunks of 7168, down accumulates into out_x ---
  for (int c = 0; c < 2; ++c) {
    transpose_cvt<<<dim3(ICH / 64, HID / 64), 256, 0, stream>>>(gw + (size_t)c * ICH, wS0,
                                                                INTERDIM, HID);
    gemm8p<1><<<dim3(ICH / 256, 16), 512, 0, stream>>>(x2, HID, wS0, HID, gateC, ICH, HID);
    transpose_cvt<<<dim3(ICH / 64, HID / 64), 256, 0, stream>>>(uw + (size_t)c * ICH, wS1,
                                                                INTERDIM, HID);
    gemm8p<1><<<dim3(ICH / 256, 16), 512, 0, stream>>>(x2, HID, wS1, HID, upC, ICH, HID);
    int n16 = (int)((size_t)NTOK * ICH / 8);
    swiglu_k<<<(n16 + 255) / 256, 256, 0, stream>>>(gateC, upC, interC, n16);
    transpose_cvt<<<dim3(HID / 64, ICH / 64), 256, 0, stream>>>(dw + (size_t)c * ICH * HID, wS0,
                                                                HID, ICH);
    if (c == 0)
      gemm8p<0><<<dim3(HID / 256, 16), 512, 0, stream>>>(interC, ICH, wS0, ICH, out_x, HID, ICH);
    else
      gemm8p<2><<<dim3(HID / 256, 16), 512, 0, stream>>>(interC, ICH, wS0, ICH, out_x, HID, ICH);
  }

  // --- phase 11: final norm (in-place on out_x) ---
  rms_out<<<NTOK, 448, 0, stream>>>(out_x, w_po, out_x);
}